// Round 2
// baseline (83.689 us; speedup 1.0000x reference)
//
#include <hip/hip_runtime.h>
#include <hip/hip_bf16.h>
#include <math.h>

#define N_ 256
#define C_ 100
#define D_ 512
#define LOG2E 1.44269504088896f
#define XPST 102                 // XPn LDS row stride (floats); bank stride 6 -> <=2-way conflicts
#define PBROWB 64                // bytes per row per k-slab in Pb (32 bf16)
#define PBSLAB 6464              // bytes per slab: 101 rows * 64B (row 100 = X_b)

// LDS layout (bytes)
#define OFF_PB    0
#define OFF_XPN   103424         // 16*6464
#define OFF_TL    156056         // + 129*102*4
#define OFF_HIST  157080
#define OFF_SPS   157480
#define OFF_RED   157928
#define OFF_S2    157960
#define LDS_TOTAL 157992         // < 163840

typedef __attribute__((ext_vector_type(8))) short short8;
typedef __attribute__((ext_vector_type(4))) float floatx4;

__device__ inline float waveReduceSum(float v) {
    #pragma unroll
    for (int off = 32; off > 0; off >>= 1) v += __shfl_xor(v, off, 64);
    return v;
}
__device__ inline float clip1(float x) { return fminf(fmaxf(x, -1.0f), 1.0f); }

__device__ inline short8 cvt8(float4 a, float4 b) {
    union { __hip_bfloat16 h[8]; short8 s; } u;
    u.h[0] = __float2bfloat16(a.x); u.h[1] = __float2bfloat16(a.y);
    u.h[2] = __float2bfloat16(a.z); u.h[3] = __float2bfloat16(a.w);
    u.h[4] = __float2bfloat16(b.x); u.h[5] = __float2bfloat16(b.y);
    u.h[6] = __float2bfloat16(b.z); u.h[7] = __float2bfloat16(b.w);
    return u.s;
}

// Fully fused, ZERO-workspace kernel. Block b self-contains:
//  phase 0: stage P->LDS bf16 (slab layout) + P-norms (deterministic per-wave
//           reduce) + X_b appended as Pb row 100 + sxb; T->LDS; hist zero.
//  phase 1: 9 row-tiles x 7 col-tiles of 16x16x32 bf16 MFMA computing
//           XPn[lr][c] = 9 * <x_(b+lr), p_c> / (||x|| ||p||) for lr=0..128,
//           c=0..99, and col 100 = 9*cos(x_(b+lr), x_b) (the pair-g column).
//           X-row norms folded into the A-loader (f32 squares + shfl).
//  phase 2: cyclic pair decomposition: slot m=t>>1: d=m+1 in [1,128]
//           (d=128 only for b<128; each unordered pair exactly once —
//           formula verified swap-symmetric), m==128 = diagonal (real loss,
//           lam=1 exact reduction). 2-lane class split, LSE over 100 classes
//           from LDS. One atomicAdd(out, partial/cnt) per block.
__global__ __launch_bounds__(512)
void fused_kernel(const float* __restrict__ X, const float* __restrict__ P,
                  const int* __restrict__ T, float* __restrict__ out) {
    extern __shared__ char smem[];
    short* Pb   = (short*)(smem + OFF_PB);
    float* XPn  = (float*)(smem + OFF_XPN);
    int*   Tl   = (int*)(smem + OFF_TL);
    int*   hist = (int*)(smem + OFF_HIST);
    float* sps  = (float*)(smem + OFF_SPS);
    float* red  = (float*)(smem + OFF_RED);
    float* s2   = (float*)(smem + OFF_S2);

    int t = threadIdx.x;
    int w = t >> 6, lane = t & 63;
    int b = blockIdx.x;

    if (t < C_) hist[t] = 0;
    if (t < N_) Tl[t] = T[t];

    // ---- phase 0: stage P -> Pb (bf16) + sps (P-norm scales) ----
    for (int j = 0; j < 13; ++j) {
        int ch = t + 512 * j;                    // chunk = (row pr, 8 elems)
        float s8 = 0.0f;
        if (ch < 6400) {
            int pr = ch >> 6, cl = ch & 63;
            const float4* pp = (const float4*)(P + (size_t)pr * D_ + cl * 8);
            float4 a = pp[0], c4 = pp[1];
            s8 = a.x*a.x + a.y*a.y + a.z*a.z + a.w*a.w
               + c4.x*c4.x + c4.y*c4.y + c4.z*c4.z + c4.w*c4.w;
            short8 v = cvt8(a, c4);
            *(short8*)((char*)Pb + (cl >> 2) * PBSLAB + pr * PBROWB + (cl & 3) * 16) = v;
        }
        float rs = waveReduceSum(s8);            // wave w, iter j owns row w+8j
        int pr0 = w + 8 * j;
        if (lane == 0 && pr0 < C_) sps[pr0] = 3.0f * rsqrtf(fmaxf(rs, 1e-24f));
    }
    // stage X_b as Pb row 100 (g-column operand)
    if (t < 64) {
        const float4* xp = (const float4*)(X + (size_t)b * D_ + t * 8);
        short8 v = cvt8(xp[0], xp[1]);
        *(short8*)((char*)Pb + (t >> 2) * PBSLAB + 100 * PBROWB + (t & 3) * 16) = v;
    }
    // sxb = 3/||x_b|| (redundant per wave, f32-exact)
    float sxb;
    {
        const float4* xp = (const float4*)(X + (size_t)b * D_ + lane * 8);
        float4 a = xp[0], c4 = xp[1];
        float xb2 = a.x*a.x + a.y*a.y + a.z*a.z + a.w*a.w
                  + c4.x*c4.x + c4.y*c4.y + c4.z*c4.z + c4.w*c4.w;
        xb2 = waveReduceSum(xb2);
        sxb = 3.0f * rsqrtf(fmaxf(xb2, 1e-24f));
    }

    __syncthreads();                             // b1: Pb, sps, Tl, hist0 ready

    if (t < N_) atomicAdd(&hist[Tl[t]], 1);

    // ---- phase 1: MFMA slice GEMM ----
    int r = lane & 15, quad = lane >> 4;
    int boff[7];
    #pragma unroll
    for (int tn = 0; tn < 7; ++tn) {
        int cb = tn * 16 + r;
        if (cb > 100) cb = 0;                    // pad cols read garbage row 0 (discarded)
        boff[tn] = cb * PBROWB + quad * 16;
    }
    for (int rt = w; rt < 9; rt += 8) {          // wave 0 also takes tile 8
        int lr0 = rt * 16;
        int ra = (b + lr0 + r) & 255;
        const float* arow = X + (size_t)ra * D_;
        floatx4 acc[7];
        #pragma unroll
        for (int tn = 0; tn < 7; ++tn) acc[tn] = (floatx4){0.f, 0.f, 0.f, 0.f};
        float nrm = 0.0f;
        #pragma unroll 4
        for (int kc = 0; kc < D_; kc += 32) {
            const float4* ap = (const float4*)(arow + kc + quad * 8);
            float4 a0 = ap[0], a1 = ap[1];
            nrm += a0.x*a0.x + a0.y*a0.y + a0.z*a0.z + a0.w*a0.w
                 + a1.x*a1.x + a1.y*a1.y + a1.z*a1.z + a1.w*a1.w;
            short8 av = cvt8(a0, a1);
            const char* sl = (const char*)Pb + (kc >> 5) * PBSLAB;
            #pragma unroll
            for (int tn = 0; tn < 7; ++tn) {
                short8 bv = *(const short8*)(sl + boff[tn]);
                acc[tn] = __builtin_amdgcn_mfma_f32_16x16x32_bf16(av, bv, acc[tn], 0, 0, 0);
            }
        }
        // fold: lane (r,*) -> f32 norm of row lr0+r
        nrm += __shfl_xor(nrm, 16, 64);
        nrm += __shfl_xor(nrm, 32, 64);
        float sxa = 3.0f * rsqrtf(fmaxf(nrm, 1e-24f));
        float sxr[4];
        #pragma unroll
        for (int i = 0; i < 4; ++i) sxr[i] = __shfl(sxa, quad * 4 + i, 64);
        #pragma unroll
        for (int tn = 0; tn < 7; ++tn) {
            int colw = tn * 16 + r;              // C/D: col=lane&15, row=quad*4+i (m89)
            if (colw <= 100) {
                float cs = (colw < 100) ? sps[colw] : sxb;
                #pragma unroll
                for (int i = 0; i < 4; ++i) {
                    int lr = lr0 + quad * 4 + i;
                    if (lr <= 128) XPn[lr * XPST + colw] = acc[tn][i] * sxr[i] * cs;
                }
            }
        }
    }
    __syncthreads();                             // b2: XPn + hist ready

    // ---- count partials ----
    float same = 0.0f;
    if (t < C_) { float n = (float)hist[t]; same = 0.5f * n * (n - 1.0f); }
    float rsame = waveReduceSum(same);
    if (lane == 0) s2[w] = rsame;

    // ---- phase 2: pairs + real ----
    int m = t >> 1, p = t & 1;
    bool diag = (m == 128);
    int d = m + 1;
    int lr2 = diag ? 0 : d;
    int i2 = diag ? b : ((b + d) & 255);
    bool isPair = (m < 127) || (m == 127 && b < 128);
    int t1 = Tl[b], t2 = Tl[i2];
    bool act = diag || (isPair && (t2 != t1));
    float contrib = 0.0f;
    if (__ballot(act)) {
        if (act) {
            const float* rowA = XPn;                 // lr = 0 (row b), broadcast
            const float* rowB = XPn + lr2 * XPST;
            float ip11 = rowA[t1], ip12 = rowA[t2];
            float ip21 = rowB[t1], ip22 = rowB[t2];
            float X1P1 = clip1(ip11), X1P2 = clip1(ip12);
            float X2P1 = clip1(ip21), X2P2 = clip1(ip22);
            float num = X2P2 - X2P1;
            float den = num + X1P1 - X1P2;
            float lam = fminf(fmaxf(num / den, 0.3f), 0.7f);
            if (diag) lam = 1.0f;                    // exact real-loss reduction
            float oml = 1.0f - lam;
            float g = rowB[100];                     // 9*cos(x_i2, x_b)
            float wn2 = 9.0f * (lam * lam + oml * oml) + 2.0f * lam * oml * g;
            float ss2 = 6.0f * rsqrtf(fmaxf(wn2, 1e-24f));
            float la = ss2 * lam * LOG2E, lb = ss2 * oml * LOG2E;
            float sm0 = 0, sm1 = 0, sm2 = 0, sm3 = 0;
            #pragma unroll 4
            for (int k = 0; k < 13; ++k) {
                int c = 4 * p + 8 * k;
                if (c < C_) {
                    sm0 += exp2f(la * rowA[c]     + lb * rowB[c]);
                    sm1 += exp2f(la * rowA[c + 1] + lb * rowB[c + 1]);
                    sm2 += exp2f(la * rowA[c + 2] + lb * rowB[c + 2]);
                    sm3 += exp2f(la * rowA[c + 3] + lb * rowB[c + 3]);
                }
            }
            float sm = (sm0 + sm1) + (sm2 + sm3);
            sm += __shfl_xor(sm, 1, 64);             // partner phase, same act
            if (p == 0) {
                float LSE = logf(sm);
                float ec1 = ss2 * (lam * ip11 + oml * ip21);
                float ec2 = ss2 * (lam * ip12 + oml * ip22);
                contrib = LSE - lam * ec1 - oml * ec2;
            }
        }
    }
    contrib = waveReduceSum(contrib);
    if (lane == 0) red[w] = contrib;
    __syncthreads();                             // b3
    if (t == 0) {
        float bs = 0.0f, sc = 0.0f;
        #pragma unroll
        for (int k = 0; k < 8; ++k) { bs += red[k]; sc += s2[k]; }
        atomicAdd(out, bs / (32896.0f - sc));
    }
}

extern "C" void kernel_launch(void* const* d_in, const int* in_sizes, int n_in,
                              void* d_out, int out_size, void* d_ws, size_t ws_size,
                              hipStream_t stream) {
    const float* X = (const float*)d_in[0];   // (256, 512) f32
    const float* P = (const float*)d_in[1];   // (100, 512) f32
    const int*   T = (const int*)d_in[2];     // (256,) i32
    // d_in[3] = indices, unused; d_ws: UNUSED (zero-workspace kernel)
    float* out = (float*)d_out;

    static bool init = false;
    if (!init) {
        hipFuncSetAttribute((const void*)fused_kernel,
                            hipFuncAttributeMaxDynamicSharedMemorySize, LDS_TOTAL);
        init = true;
    }
    fused_kernel<<<N_, 512, LDS_TOTAL, stream>>>(X, P, T, out);
}

// Round 3
// 76.608 us; speedup vs baseline: 1.0924x; 1.0924x over previous
//
#include <hip/hip_runtime.h>
#include <hip/hip_bf16.h>
#include <math.h>

#define N_ 256
#define C_ 100
#define D_ 512
#define LOG2E 1.44269504088896f

// ---- workspace layout (bytes) ----
// Xf: [16 k-slabs][256 rows][64B]  (bf16 frag-native: row-major 64B per row per slab)
// Pf: [16 k-slabs][100 rows][64B]
#define WS_XF   0
#define WS_PF   262144
#define WS_SXS  364544          // 256 f32 scales 3/||x||
#define WS_SPS  365568          // 100 f32 scales 3/||p||

// ---- K1 LDS layout (bytes) ----
#define PB_SLAB   6656          // 104 rows * 64B (rows 100=x_b, 101..103 pad/garbage)
#define OFF_PB    0             // 16*6656 = 106496
#define XPST      104           // XPn row stride (f32) -> 16B-aligned float4 rows
#define OFF_XPN   106496        // 129*104*4 = 53664
#define OFF_SXS   160160        // 1024
#define OFF_SPS   161184        // 400
#define OFF_TL    161600        // 1024
#define OFF_HIST  162624        // 400
#define OFF_RED   163024        // 32
#define OFF_S2    163056        // 32
#define LDS_TOTAL 163088        // <= 163840

typedef __attribute__((ext_vector_type(8))) short short8;
typedef __attribute__((ext_vector_type(4))) float floatx4;

__device__ inline float waveReduceSum(float v) {
    #pragma unroll
    for (int off = 32; off > 0; off >>= 1) v += __shfl_xor(v, off, 64);
    return v;
}
__device__ inline float clip1(float x) { return fminf(fmaxf(x, -1.0f), 1.0f); }

__device__ inline short8 cvt8(float4 a, float4 b) {
    union { __hip_bfloat16 h[8]; short8 s; } u;
    u.h[0] = __float2bfloat16(a.x); u.h[1] = __float2bfloat16(a.y);
    u.h[2] = __float2bfloat16(a.z); u.h[3] = __float2bfloat16(a.w);
    u.h[4] = __float2bfloat16(b.x); u.h[5] = __float2bfloat16(b.y);
    u.h[6] = __float2bfloat16(b.z); u.h[7] = __float2bfloat16(b.w);
    return u.s;
}

// K0: one wave per row (356 rows = X then P): f32 load -> norm scale (f32 exact,
// same math as validated R2) + bf16 cvt -> frag-native ws layout. Amortizes all
// cvt/norm work ONCE instead of per-block.
__global__ __launch_bounds__(256)
void prep_kernel(const float* __restrict__ X, const float* __restrict__ P,
                 char* __restrict__ ws) {
    int w = blockIdx.x * 4 + (threadIdx.x >> 6);
    if (w >= 356) return;
    int lane = threadIdx.x & 63;
    bool isX = (w < N_);
    int rrow = isX ? w : (w - N_);
    const float* src = isX ? (X + (size_t)w * D_) : (P + (size_t)(w - N_) * D_);
    const float4* sp4 = (const float4*)src + lane * 2;
    float4 a = sp4[0], b2 = sp4[1];
    float s8 = a.x*a.x + a.y*a.y + a.z*a.z + a.w*a.w
             + b2.x*b2.x + b2.y*b2.y + b2.z*b2.z + b2.w*b2.w;
    float tot = waveReduceSum(s8);
    float sc = 3.0f * rsqrtf(fmaxf(tot, 1e-24f));
    if (lane == 0) {
        if (isX) ((float*)(ws + WS_SXS))[rrow] = sc;
        else     ((float*)(ws + WS_SPS))[rrow] = sc;
    }
    short8 v = cvt8(a, b2);
    char* base = ws + (isX ? WS_XF : WS_PF);
    int rowsN = isX ? 256 : 100;
    // lane holds k = lane*8..lane*8+7 -> slab = lane>>2, 16B chunk (lane&3)
    *(short8*)(base + ((size_t)(lane >> 2) * rowsN + rrow) * 64 + (lane & 3) * 16) = v;
}

// K1: block b (256 blocks, 512 thr). Phases:
//  P0: linear conflict-free copy Pf->Pb LDS (pre-swizzled layout) + x_b as Pb
//      row 100 + sxs/sps/T -> LDS; hist.
//  P1: XPn[lr][c] = scaled IPs for rows b..b+127 (lr 0..127) x cols 0..100
//      (col 100 = x_b g-column). 8 waves = (rt-pair w>>1: {rh, rh+4}) x
//      (ct-half w&1: {0..3} / {4..6}): A loaded once per 2 MFMAs, each
//      B-frag read 4x (not 8x). b<128: extra tile rt=8 (row 128 = d-128
//      partner) on waves 6,7 only. Pure bf16 16B loads + MFMA (no cvt).
//  P2: 128 slots x 4 lanes: slot m<127 -> pair d=m+1; slot 127 -> diag
//      (lam=1 exact real-loss) + (b<128) the d=128 pair. 7-iter LSE/lane.
// Math identical to validated R2 kernel.
__global__ __launch_bounds__(512)
void fused_kernel(const char* __restrict__ ws, const int* __restrict__ T,
                  float* __restrict__ out) {
    extern __shared__ char smem[];
    char*  PbC   = smem + OFF_PB;
    float* XPn   = (float*)(smem + OFF_XPN);
    float* sxs_l = (float*)(smem + OFF_SXS);
    float* sps_l = (float*)(smem + OFF_SPS);
    int*   Tl    = (int*)(smem + OFF_TL);
    int*   hist  = (int*)(smem + OFF_HIST);
    float* red   = (float*)(smem + OFF_RED);
    float* s2    = (float*)(smem + OFF_S2);

    int t = threadIdx.x;
    int w = t >> 6, lane = t & 63;
    int b = blockIdx.x;
    const char* Xfc = ws + WS_XF;
    const char* Pfc = ws + WS_PF;

    // ---- P0: staging ----
    #pragma unroll
    for (int it = 0; it < 13; ++it) {
        int id = t + 512 * it;                    // 16B chunk id over Pf (6400)
        if (id < 6400) {
            int slab = id / 400;                  // 400 chunks per slab
            int within = id - slab * 400;
            *(short8*)(PbC + slab * PB_SLAB + within * 16) =
                *(const short8*)(Pfc + (size_t)slab * 6400 + within * 16);
        }
    }
    if (t < 64) {                                 // x_b -> Pb row 100 (g-column)
        *(short8*)(PbC + (t >> 2) * PB_SLAB + 6400 + (t & 3) * 16) =
            *(const short8*)(Xfc + ((size_t)(t >> 2) * 256 + b) * 64 + (t & 3) * 16);
    }
    if (t < N_) { sxs_l[t] = ((const float*)(ws + WS_SXS))[t]; Tl[t] = T[t]; }
    if (t < C_) { sps_l[t] = ((const float*)(ws + WS_SPS))[t]; hist[t] = 0; }
    __syncthreads();                              // b1
    if (t < N_) atomicAdd(&hist[Tl[t]], 1);

    // ---- P1: MFMA slice ----
    int r = lane & 15, quad = lane >> 4;
    int rh = w >> 1, ch = w & 1;
    int ra0 = (b + rh * 16 + r) & 255;
    int ra1 = (b + (rh + 4) * 16 + r) & 255;
    int aoff0 = ra0 * 64 + quad * 16;
    int aoff1 = ra1 * 64 + quad * 16;
    int ct0 = ch ? 4 : 0, nct = ch ? 3 : 4;
    int boff[4];
    #pragma unroll
    for (int j = 0; j < 4; ++j)
        boff[j] = ((ct0 + j) * 16 + r) * 64 + quad * 16;  // rows<=111 stay in LDS

    floatx4 acc[2][4];
    #pragma unroll
    for (int i = 0; i < 2; ++i)
        #pragma unroll
        for (int j = 0; j < 4; ++j) acc[i][j] = (floatx4){0.f, 0.f, 0.f, 0.f};

    #pragma unroll 4
    for (int ks = 0; ks < 16; ++ks) {
        const char* ab = Xfc + (size_t)ks * 16384;
        short8 a0 = *(const short8*)(ab + aoff0);
        short8 a1 = *(const short8*)(ab + aoff1);
        const char* bb = PbC + ks * PB_SLAB;
        #pragma unroll
        for (int j = 0; j < 4; ++j) {
            if (j < nct) {
                short8 bv = *(const short8*)(bb + boff[j]);
                acc[0][j] = __builtin_amdgcn_mfma_f32_16x16x32_bf16(a0, bv, acc[0][j], 0, 0, 0);
                acc[1][j] = __builtin_amdgcn_mfma_f32_16x16x32_bf16(a1, bv, acc[1][j], 0, 0, 0);
            }
        }
    }
    // store: C/D col=lane&15, row=quad*4+i (validated m89/R2)
    #pragma unroll
    for (int rtid = 0; rtid < 2; ++rtid) {
        int rt = rtid ? (rh + 4) : rh;
        #pragma unroll
        for (int j = 0; j < 4; ++j) {
            if (j < nct) {
                int c = (ct0 + j) * 16 + r;
                if (c <= 100) {
                    float cs = (c < 100) ? sps_l[c] : sxs_l[b];
                    #pragma unroll
                    for (int i = 0; i < 4; ++i) {
                        int lr = rt * 16 + quad * 4 + i;
                        XPn[lr * XPST + c] = acc[rtid][j][i] * sxs_l[(b + lr) & 255] * cs;
                    }
                }
            }
        }
    }
    // b<128: row-128 tile (rows 128..143, only lr=128 kept), waves 6 & 7
    if (b < 128 && rh == 3) {
        int ra8 = (b + 128 + r) & 255;
        int aoff8 = ra8 * 64 + quad * 16;
        floatx4 acc8[4];
        #pragma unroll
        for (int j = 0; j < 4; ++j) acc8[j] = (floatx4){0.f, 0.f, 0.f, 0.f};
        #pragma unroll 4
        for (int ks = 0; ks < 16; ++ks) {
            short8 a8 = *(const short8*)(Xfc + (size_t)ks * 16384 + aoff8);
            const char* bb = PbC + ks * PB_SLAB;
            #pragma unroll
            for (int j = 0; j < 4; ++j) {
                if (j < nct) {
                    short8 bv = *(const short8*)(bb + boff[j]);
                    acc8[j] = __builtin_amdgcn_mfma_f32_16x16x32_bf16(a8, bv, acc8[j], 0, 0, 0);
                }
            }
        }
        if (quad == 0) {                          // lr = 128 lives at quad0,i=0
            #pragma unroll
            for (int j = 0; j < 4; ++j) {
                if (j < nct) {
                    int c = (ct0 + j) * 16 + r;
                    if (c <= 100) {
                        float cs = (c < 100) ? sps_l[c] : sxs_l[b];
                        XPn[128 * XPST + c] = acc8[j][0] * sxs_l[(b + 128) & 255] * cs;
                    }
                }
            }
        }
    }
    __syncthreads();                              // b2: XPn + hist ready

    // ---- count partials ----
    float same = 0.0f;
    if (t < C_) { float n = (float)hist[t]; same = 0.5f * n * (n - 1.0f); }
    float rsame = waveReduceSum(same);
    if (lane == 0) s2[w] = rsame;

    // ---- P2: pairs + real ----
    int m = t >> 2, q = t & 3;
    int t1 = Tl[b];
    float contrib = 0.0f;
    int nit = (m == 127) ? ((b < 128) ? 2 : 1) : 1;
    for (int it = 0; it < nit; ++it) {
        bool isdiag = (m == 127) && (it == 0);
        int dd = isdiag ? 0 : ((m == 127) ? 128 : (m + 1));
        int i2 = (b + dd) & 255;
        int t2 = Tl[i2];
        if (!(isdiag || (t2 != t1))) continue;    // group-uniform branch
        const float* rowA = XPn;                  // row b (lr 0)
        const float* rowB = XPn + dd * XPST;
        float ip11 = rowA[t1], ip12 = rowA[t2];
        float ip21 = rowB[t1], ip22 = rowB[t2];
        float X1P1 = clip1(ip11), X1P2 = clip1(ip12);
        float X2P1 = clip1(ip21), X2P2 = clip1(ip22);
        float num = X2P2 - X2P1;
        float den = num + X1P1 - X1P2;
        float lam = fminf(fmaxf(num / den, 0.3f), 0.7f);
        if (isdiag) lam = 1.0f;                   // exact real-loss reduction
        float oml = 1.0f - lam;
        float g = rowB[100];                      // 9*cos(x_i2, x_b)
        float wn2 = 9.0f * (lam * lam + oml * oml) + 2.0f * lam * oml * g;
        float ss2 = 6.0f * rsqrtf(fmaxf(wn2, 1e-24f));
        float la = ss2 * lam * LOG2E, lb = ss2 * oml * LOG2E;
        float sm = 0.0f;
        #pragma unroll
        for (int k = 0; k < 7; ++k) {
            int c = q * 4 + 16 * k;
            if (c < C_) {
                float4 a1 = *(const float4*)(rowA + c);
                float4 a2 = *(const float4*)(rowB + c);
                sm += exp2f(la * a1.x + lb * a2.x);
                sm += exp2f(la * a1.y + lb * a2.y);
                sm += exp2f(la * a1.z + lb * a2.z);
                sm += exp2f(la * a1.w + lb * a2.w);
            }
        }
        sm += __shfl_xor(sm, 1, 64);
        sm += __shfl_xor(sm, 2, 64);
        if (q == 0) {
            float LSE = logf(sm);
            float ec1 = ss2 * (lam * ip11 + oml * ip21);
            float ec2 = ss2 * (lam * ip12 + oml * ip22);
            contrib += LSE - lam * ec1 - oml * ec2;
        }
    }
    contrib = waveReduceSum(contrib);
    if (lane == 0) red[w] = contrib;
    __syncthreads();                              // b3
    if (t == 0) {
        float bs = 0.0f, sc = 0.0f;
        #pragma unroll
        for (int k = 0; k < 8; ++k) { bs += red[k]; sc += s2[k]; }
        atomicAdd(out, bs / (32896.0f - sc));
    }
}

extern "C" void kernel_launch(void* const* d_in, const int* in_sizes, int n_in,
                              void* d_out, int out_size, void* d_ws, size_t ws_size,
                              hipStream_t stream) {
    const float* X = (const float*)d_in[0];   // (256, 512) f32
    const float* P = (const float*)d_in[1];   // (100, 512) f32
    const int*   T = (const int*)d_in[2];     // (256,) i32
    // d_in[3] = indices, unused
    char* ws = (char*)d_ws;                   // ~358 KB used
    float* out = (float*)d_out;

    static bool init = false;
    if (!init) {
        hipFuncSetAttribute((const void*)fused_kernel,
                            hipFuncAttributeMaxDynamicSharedMemorySize, LDS_TOTAL);
        init = true;
    }
    prep_kernel<<<89, 256, 0, stream>>>(X, P, ws);
    fused_kernel<<<N_, 512, LDS_TOTAL, stream>>>(ws, T, out);
}